// Round 6
// baseline (8451.638 us; speedup 1.0000x reference)
//
#include <hip/hip_runtime.h>
#include <math.h>

// TinyRecursiveModelTRMv6 — fp32, round 6.
// Arithmetic VERBATIM round-1/5 (bit-identical). Pure resource changes:
//  - LDS diet: two 132-wide buffers (sA,sB ~16.9KB each, ~35KB total) instead of
//    132+260 (50.5KB). 256-wide tiles (h, ai) split column-wise across sA/sB;
//    their K=256 GEMMs become two K=128 mm_blocks over the SAME accumulator in
//    the SAME ascending k-order -> bit-identical.  -> 4 blocks/CU (was 3).
//  - __launch_bounds__(256,4).
//  - mm_block A-operand reads vectorized to float4 LDS loads (rows 16B-aligned),
//    same FMA order per accumulator -> bit-identical.
//  - KV history cache kept (proven bitwise-safe; recompute fallback on ws_size).
// Launches: prep, (stepK<i>, redK<i>) x5, final.

#define BATCH 65536
#define D 128
#define BD ((size_t)BATCH * D)
#define NSTEP 5
#define ROWS 32
#define NTHR 256
#define NBLK (BATCH / ROWS)          // 2048
#define LN_EPS 1e-5f
#define ATT_SCALE 0.08838834764831845f   // 128^-0.5
#define LDU 132                      // both LDS buffers; 132*4B=528B rows (16B-aligned)

// ---- workspace layout (float offsets) ----
#define WS_Z    ((size_t)0)
#define WS_H1   (BD)                              // 5 x B x D : ZH (recompute) or KH (kv)
#define WS_PART (WS_H1 + 5*BD)                    // NBLK x 4
#define WS_SCAL (WS_PART + (size_t)NBLK*4)        // 2048 floats
#define WS_H2   (WS_SCAL + 2048)                  // 5 x B x D : VH (kv mode only)
#define WS_KV_END (WS_H2 + 5*BD)

// scalar-block sub-offsets (floats)
#define SC_FS   0
#define SC_B02  1
#define SC_CSUM 2
#define SC_FUT  16
#define SC_MEM  256
#define SC_R10  960

struct Args {
  const float *x, *y_init, *affect;
  const float *g_lat, *b_lat, *g_ans, *b_ans, *g_z, *b_z;
  const float *lw1, *lb1, *lw2, *lb2;
  const float *aw1, *ab1, *aw2, *ab2;
  const float *affw, *affb, *gw, *gb;
  const float *qw, *qb, *kw, *kb, *vw, *vb, *ow, *ob;
  const float *pw1, *pb1, *pw2, *pb2;
  float *Y, *conf, *pad;            // d_out regions
  float *Z, *H1, *H2, *PART, *SCAL; // ws regions
  int useKV;
};

__device__ __forceinline__ float4 ld4(const float* p) { return *(const float4*)p; }
__device__ __forceinline__ void st4(float* p, float4 v) { *(float4*)p = v; }
__device__ __forceinline__ float geluf(float v) { return 0.5f*v*(1.0f + erff(v*0.70710678118654752f)); }
__device__ __forceinline__ float dot4(float4 a, float4 b){ return a.x*b.x + a.y*b.y + a.z*b.z + a.w*b.w; }
__device__ __forceinline__ void accSQ(float4 v, float& S, float& Q) {
  S += v.x+v.y+v.z+v.w;
  Q += v.x*v.x + v.y*v.y + v.z*v.z + v.w*v.w;
}
__device__ __forceinline__ float getf(const float4& v, int i) {
  return i==0 ? v.x : (i==1 ? v.y : (i==2 ? v.z : v.w));
}

// Register-tiled block GEMM: 32 rows x (32*NPT) cols, A staged in LDS [32][LDU],
// W streamed row-major [KDIM][N] from global. Thread (rg,cg) -> rows rg*4..+3,
// cols cg*NPT..+NPT. A-reads are float4 (rows 16B-aligned); per-accumulator
// FMA order is k-ascending, identical to the scalar version (bit-identical).
template<int KDIM, int NPT>
__device__ __forceinline__ void mm_block(const float* __restrict__ W, int N,
                                         const float* As, int lda,
                                         int rg, int cg, float (&acc)[4][NPT])
{
  const float* a0 = As + (rg*4+0)*lda;
  const float* a1 = As + (rg*4+1)*lda;
  const float* a2 = As + (rg*4+2)*lda;
  const float* a3 = As + (rg*4+3)*lda;
  const float* wp = W + cg*NPT;
  #pragma unroll 2
  for (int k4 = 0; k4 < KDIM/4; ++k4) {
    float4 av0 = ld4(a0 + k4*4);
    float4 av1 = ld4(a1 + k4*4);
    float4 av2 = ld4(a2 + k4*4);
    float4 av3 = ld4(a3 + k4*4);
    #pragma unroll
    for (int kk = 0; kk < 4; ++kk) {
      const int k = k4*4 + kk;
      float w[NPT];
      if constexpr (NPT == 8) {
        float4 w0 = ld4(wp + (size_t)k*N);
        float4 w1 = ld4(wp + (size_t)k*N + 4);
        w[0]=w0.x; w[1]=w0.y; w[2]=w0.z; w[3]=w0.w;
        w[4]=w1.x; w[5]=w1.y; w[6]=w1.z; w[7]=w1.w;
      } else if constexpr (NPT == 4) {
        float4 w0 = ld4(wp + (size_t)k*N);
        w[0]=w0.x; w[1]=w0.y; w[2]=w0.z; w[3]=w0.w;
      } else {
        float2 w0 = *(const float2*)(wp + (size_t)k*N);
        w[0]=w0.x; w[1]=w0.y;
      }
      float e0 = getf(av0,kk), e1 = getf(av1,kk), e2 = getf(av2,kk), e3 = getf(av3,kk);
      #pragma unroll
      for (int c = 0; c < NPT; ++c) {
        acc[0][c] += e0*w[c];
        acc[1][c] += e1*w[c];
        acc[2][c] += e2*w[c];
        acc[3][c] += e3*w[c];
      }
    }
  }
}

// z = LN(z + add) over d=128 (reads/writes global Z).
__device__ __forceinline__ void z_ln_update(const Args& A, int row0, int rg, int cg,
                                            const float (&add)[4][4])
{
  float4 g4 = ld4(A.g_z + cg*4);
  float4 b4 = ld4(A.b_z + cg*4);
  #pragma unroll
  for (int rr = 0; rr < 4; ++rr) {
    size_t off = (size_t)(row0 + rg*4 + rr)*D + cg*4;
    float4 z = ld4(A.Z + off);
    float v0 = z.x + add[rr][0];
    float v1 = z.y + add[rr][1];
    float v2 = z.z + add[rr][2];
    float v3 = z.w + add[rr][3];
    float S = v0+v1+v2+v3;
    float Q = v0*v0+v1*v1+v2*v2+v3*v3;
    S += __shfl_xor(S,1);  Q += __shfl_xor(Q,1);
    S += __shfl_xor(S,2);  Q += __shfl_xor(Q,2);
    S += __shfl_xor(S,4);  Q += __shfl_xor(Q,4);
    S += __shfl_xor(S,8);  Q += __shfl_xor(Q,8);
    S += __shfl_xor(S,16); Q += __shfl_xor(Q,16);
    float m  = S*(1.f/128.f);
    float rs = rsqrtf(Q*(1.f/128.f) - m*m + LN_EPS);
    float4 o;
    o.x = (v0-m)*rs*g4.x + b4.x;
    o.y = (v1-m)*rs*g4.y + b4.y;
    o.z = (v2-m)*rs*g4.z + b4.z;
    o.w = (v3-m)*rs*g4.w + b4.w;
    st4(A.Z + off, o);
  }
}

__device__ __forceinline__ void stage_raw(float* sA, const float* src, int row0, int t)
{
  for (int e4 = t; e4 < ROWS*32; e4 += NTHR) {
    int r = e4 >> 5, c4 = e4 & 31;
    st4(sA + r*LDU + c4*4, ld4(src + (size_t)(row0+r)*D + c4*4));
  }
}

// Epilogue of previous outer step: z = (z*fs)*(1-b02)+b02*future ; answer LN+MLP ; y += 0.4*dy
// 256-wide tiles split: cols 0..127 -> sA, 128..255 -> sB (same k-order in GEMMs).
__device__ __forceinline__ void epilogue_phase(const Args& A, float* sA, float* sB,
                                               float* sM, float* sR,
                                               int row0, int t, int rg, int cg, int r8, int sub)
{
  const float fs  = A.SCAL[SC_FS];
  const float b02 = A.SCAL[SC_B02];
  const float a   = fs*(1.0f - b02);
  for (int e4 = t; e4 < ROWS*32; e4 += NTHR) {
    int r = e4 >> 5, c4 = e4 & 31;
    size_t off = (size_t)(row0 + r)*D + c4*4;
    float4 z = ld4(A.Z + off);
    float4 f = ld4(A.SCAL + SC_FUT + c4*4);
    z.x = z.x*a + b02*f.x;
    z.y = z.y*a + b02*f.y;
    z.z = z.z*a + b02*f.z;
    z.w = z.w*a + b02*f.w;
    st4(A.Z + off, z);
  }
  __syncthreads();
  { // LN stats over [y,z] (256)
    const float* yr = A.Y + (size_t)(row0 + r8)*D;
    const float* zr = A.Z + (size_t)(row0 + r8)*D;
    float S = 0.f, Q = 0.f;
    #pragma unroll
    for (int j = 0; j < 4; ++j) {
      int c = (sub + 8*j)*4;
      accSQ(ld4(yr + c), S, Q);
      accSQ(ld4(zr + c), S, Q);
    }
    S += __shfl_xor(S,1); Q += __shfl_xor(Q,1);
    S += __shfl_xor(S,2); Q += __shfl_xor(Q,2);
    S += __shfl_xor(S,4); Q += __shfl_xor(Q,4);
    if (sub == 0) {
      float m = S*(1.f/256.f);
      sM[r8] = m;
      sR[r8] = rsqrtf(Q*(1.f/256.f) - m*m + LN_EPS);
    }
  }
  __syncthreads();
  // stage ai = LN([y,z])*g+b : cols 0..127 -> sA, 128..255 -> sB
  for (int e4 = t; e4 < ROWS*64; e4 += NTHR) {
    int r = e4 >> 6, c4 = e4 & 63;
    int k = c4*4;
    float m = sM[r], rs = sR[r];
    float4 v = (k < D) ? ld4(A.Y + (size_t)(row0+r)*D + k)
                       : ld4(A.Z + (size_t)(row0+r)*D + (k - D));
    float4 g = ld4(A.g_ans + k);
    float4 b = ld4(A.b_ans + k);
    float4 o;
    o.x = (v.x-m)*rs*g.x + b.x;
    o.y = (v.y-m)*rs*g.y + b.y;
    o.z = (v.z-m)*rs*g.z + b.z;
    o.w = (v.w-m)*rs*g.w + b.w;
    float* base = (k < 128) ? sA : (sB - 128);
    st4(base + r*LDU + k, o);
  }
  __syncthreads();
  float acc[4][8] = {};
  mm_block<128,8>(A.aw1,                   256, sA, LDU, rg, cg, acc);
  mm_block<128,8>(A.aw1 + (size_t)128*256, 256, sB, LDU, rg, cg, acc);
  float4 b1a = ld4(A.ab1 + cg*8);
  float4 b1b = ld4(A.ab1 + cg*8 + 4);
  float h[4][8];
  #pragma unroll
  for (int rr = 0; rr < 4; ++rr) {
    h[rr][0]=geluf(acc[rr][0]+b1a.x); h[rr][1]=geluf(acc[rr][1]+b1a.y);
    h[rr][2]=geluf(acc[rr][2]+b1a.z); h[rr][3]=geluf(acc[rr][3]+b1a.w);
    h[rr][4]=geluf(acc[rr][4]+b1b.x); h[rr][5]=geluf(acc[rr][5]+b1b.y);
    h[rr][6]=geluf(acc[rr][6]+b1b.z); h[rr][7]=geluf(acc[rr][7]+b1b.w);
  }
  __syncthreads();
  {
    float* hb = (cg < 16) ? sA : (sB - 128);   // col = cg*8 (0..255) -> split at 128
    #pragma unroll
    for (int rr = 0; rr < 4; ++rr) {
      float4 h0; h0.x=h[rr][0]; h0.y=h[rr][1]; h0.z=h[rr][2]; h0.w=h[rr][3];
      float4 h1; h1.x=h[rr][4]; h1.y=h[rr][5]; h1.z=h[rr][6]; h1.w=h[rr][7];
      st4(hb + (rg*4+rr)*LDU + cg*8,     h0);
      st4(hb + (rg*4+rr)*LDU + cg*8 + 4, h1);
    }
  }
  __syncthreads();
  float acc2[4][4] = {};
  mm_block<128,4>(A.aw2,                   128, sA, LDU, rg, cg, acc2);
  mm_block<128,4>(A.aw2 + (size_t)128*128, 128, sB, LDU, rg, cg, acc2);
  float4 b2 = ld4(A.ab2 + cg*4);
  #pragma unroll
  for (int rr = 0; rr < 4; ++rr) {
    size_t off = (size_t)(row0 + rg*4 + rr)*D + cg*4;
    float4 y = ld4(A.Y + off);
    y.x += 0.4f*(acc2[rr][0] + b2.x);
    y.y += 0.4f*(acc2[rr][1] + b2.y);
    y.z += 0.4f*(acc2[rr][2] + b2.z);
    y.w += 0.4f*(acc2[rr][3] + b2.w);
    st4(A.Y + off, y);
  }
  __syncthreads();
}

__global__ void prepK(Args A)
{
  size_t i  = (size_t)blockIdx.x*blockDim.x + threadIdx.x;
  size_t n4 = BD/4;
  float4 zero; zero.x=0.f; zero.y=0.f; zero.z=0.f; zero.w=0.f;
  for (; i < n4; i += (size_t)gridDim.x*blockDim.x) {
    ((float4*)A.Z)[i] = zero;
    ((float4*)A.Y)[i] = ((const float4*)A.y_init)[i];
  }
}

template<int STEP>
__global__ __launch_bounds__(NTHR, 4) void stepK(Args A)
{
  __shared__ __align__(16) float sA[ROWS*LDU];
  __shared__ __align__(16) float sB[ROWS*LDU];
  __shared__ float sM[ROWS], sR[ROWS], sG[ROWS];
  __shared__ float sS[ROWS][8];
  __shared__ float sRed[4][2];

  const int t = threadIdx.x;
  const int row0 = blockIdx.x * ROWS;
  const int rg = t >> 5, cg = t & 31;
  const int r8 = t >> 3, sub = t & 7;

  if (STEP > 0)
    epilogue_phase(A, sA, sB, sM, sR, row0, t, rg, cg, r8, sub);

  // ---------------- inner latent loop (x4) — round-1 arithmetic ----------------
  #pragma unroll 1
  for (int it = 0; it < 4; ++it) {
    { // stats over cat384 = [x,y,z]
      const float* xr = A.x + (size_t)(row0 + r8)*D;
      const float* yr = A.Y + (size_t)(row0 + r8)*D;
      const float* zr = A.Z + (size_t)(row0 + r8)*D;
      float S = 0.f, Q = 0.f;
      #pragma unroll
      for (int j = 0; j < 4; ++j) {
        int c = (sub + 8*j)*4;
        accSQ(ld4(xr + c), S, Q);
        accSQ(ld4(yr + c), S, Q);
        accSQ(ld4(zr + c), S, Q);
      }
      S += __shfl_xor(S,1); Q += __shfl_xor(Q,1);
      S += __shfl_xor(S,2); Q += __shfl_xor(Q,2);
      S += __shfl_xor(S,4); Q += __shfl_xor(Q,4);
      if (sub == 0) {
        float m = S*(1.f/384.f);
        sM[r8] = m;
        sR[r8] = rsqrtf(Q*(1.f/384.f) - m*m + LN_EPS);
      }
    }
    __syncthreads();
    float acc[4][8] = {};
    #pragma unroll 1
    for (int seg = 0; seg < 3; ++seg) {  // 384 = x|y|z segments of 128
      const float* src = (seg == 0) ? A.x : (seg == 1 ? (const float*)A.Y : (const float*)A.Z);
      for (int e4 = t; e4 < ROWS*32; e4 += NTHR) {
        int r = e4 >> 5, c4 = e4 & 31;
        float4 v = ld4(src + (size_t)(row0+r)*D + c4*4);
        float m = sM[r], rs = sR[r];
        int k = seg*D + c4*4;
        float4 g = ld4(A.g_lat + k);
        float4 b = ld4(A.b_lat + k);
        float4 o;
        o.x = (v.x-m)*rs*g.x + b.x;
        o.y = (v.y-m)*rs*g.y + b.y;
        o.z = (v.z-m)*rs*g.z + b.z;
        o.w = (v.w-m)*rs*g.w + b.w;
        st4(sA + r*LDU + c4*4, o);
      }
      __syncthreads();
      mm_block<128,8>(A.lw1 + (size_t)seg*D*256, 256, sA, LDU, rg, cg, acc);
      __syncthreads();
    }
    float4 l1a = ld4(A.lb1 + cg*8);
    float4 l1b = ld4(A.lb1 + cg*8 + 4);
    {
      float* hb = (cg < 16) ? sA : (sB - 128);   // h cols split at 128
      #pragma unroll
      for (int rr = 0; rr < 4; ++rr) {
        float4 h0, h1;
        h0.x = geluf(acc[rr][0]+l1a.x); h0.y = geluf(acc[rr][1]+l1a.y);
        h0.z = geluf(acc[rr][2]+l1a.z); h0.w = geluf(acc[rr][3]+l1a.w);
        h1.x = geluf(acc[rr][4]+l1b.x); h1.y = geluf(acc[rr][5]+l1b.y);
        h1.z = geluf(acc[rr][6]+l1b.z); h1.w = geluf(acc[rr][7]+l1b.w);
        st4(hb + (rg*4+rr)*LDU + cg*8,     h0);
        st4(hb + (rg*4+rr)*LDU + cg*8 + 4, h1);
      }
    }
    __syncthreads();
    float acc2[4][4] = {};
    mm_block<128,4>(A.lw2,                   128, sA, LDU, rg, cg, acc2);
    mm_block<128,4>(A.lw2 + (size_t)128*128, 128, sB, LDU, rg, cg, acc2);
    float4 l2 = ld4(A.lb2 + cg*4);
    float add[4][4];
    #pragma unroll
    for (int rr = 0; rr < 4; ++rr) {
      add[rr][0] = 0.3f*(acc2[rr][0]+l2.x);
      add[rr][1] = 0.3f*(acc2[rr][1]+l2.y);
      add[rr][2] = 0.3f*(acc2[rr][2]+l2.z);
      add[rr][3] = 0.3f*(acc2[rr][3]+l2.w);
    }
    z_ln_update(A, row0, rg, cg, add);
    __syncthreads();
  }

  // ---------------- gate + affect ----------------
  {
    size_t row = (size_t)row0 + r8;
    const float* zr = A.Z + row*D;
    float af0 = A.affect[row*3+0];
    float af1 = A.affect[row*3+1];
    float af2 = A.affect[row*3+2];
    float dg = 0.f;
    #pragma unroll
    for (int j = 0; j < 4; ++j) {
      int c = (sub + 8*j)*4;
      float4 zv = ld4(zr + c);
      float4 g1 = ld4(A.gw + c);
      float4 g2 = ld4(A.gw + D + c);
      float4 w0 = ld4(A.affw + c);
      float4 w1 = ld4(A.affw + D + c);
      float4 w2 = ld4(A.affw + 2*D + c);
      float4 ab = ld4(A.affb + c);
      float4 al;
      al.x = tanhf(af0*w0.x + af1*w1.x + af2*w2.x + ab.x);
      al.y = tanhf(af0*w0.y + af1*w1.y + af2*w2.y + ab.y);
      al.z = tanhf(af0*w0.z + af1*w1.z + af2*w2.z + ab.z);
      al.w = tanhf(af0*w0.w + af1*w1.w + af2*w2.w + ab.w);
      st4(sA + r8*LDU + c, al);   // cache affect_latent for z-update
      dg += dot4(zv, g1) + dot4(al, g2);
    }
    dg += __shfl_xor(dg,1);
    dg += __shfl_xor(dg,2);
    dg += __shfl_xor(dg,4);
    if (sub == 0) sG[r8] = 1.f/(1.f + expf(-(dg + A.gb[0])));
  }
  __syncthreads();
  { // z += 0.3*gate*al ; recompute mode records z snapshot
    float* zhw = A.H1 + (size_t)STEP*BD;
    for (int e4 = t; e4 < ROWS*32; e4 += NTHR) {
      int r = e4 >> 5, c4 = e4 & 31;
      size_t off = (size_t)(row0+r)*D + c4*4;
      float4 z  = ld4(A.Z + off);
      float4 al = ld4(sA + r*LDU + c4*4);
      float g = 0.3f * sG[r];
      z.x += g*al.x; z.y += g*al.y; z.z += g*al.z; z.w += g*al.w;
      st4(A.Z + off, z);
      if (!A.useKV) st4(zhw + off, z);
    }
  }
  __syncthreads();

  // ---------------- snapshot staging: K/V cache + q ----------------
  float q[4][4];
  if (A.useKV || STEP > 0) {
    stage_raw(sA, A.Z, row0, t);
    __syncthreads();
  }
  if (A.useKV) {
    float kacc[4][4] = {}, vacc[4][4] = {};
    mm_block<128,4>(A.kw, 128, sA, LDU, rg, cg, kacc);
    mm_block<128,4>(A.vw, 128, sA, LDU, rg, cg, vacc);
    float4 kb4 = ld4(A.kb + cg*4);
    float4 vb4 = ld4(A.vb + cg*4);
    float* KH = A.H1 + (size_t)STEP*BD;
    float* VH = A.H2 + (size_t)STEP*BD;
    #pragma unroll
    for (int rr = 0; rr < 4; ++rr) {
      size_t off = (size_t)(row0 + rg*4 + rr)*D + cg*4;
      float4 kv; kv.x=kacc[rr][0]+kb4.x; kv.y=kacc[rr][1]+kb4.y;
                 kv.z=kacc[rr][2]+kb4.z; kv.w=kacc[rr][3]+kb4.w;
      float4 vv; vv.x=vacc[rr][0]+vb4.x; vv.y=vacc[rr][1]+vb4.y;
                 vv.z=vacc[rr][2]+vb4.z; vv.w=vacc[rr][3]+vb4.w;
      st4(KH + off, kv);   // read back only by this same thread (j==STEP)
      st4(VH + off, vv);
    }
  }
  if (STEP > 0) {
    float qacc[4][4] = {};
    mm_block<128,4>(A.qw, 128, sA, LDU, rg, cg, qacc);
    float4 qb4 = ld4(A.qb + cg*4);
    #pragma unroll
    for (int rr = 0; rr < 4; ++rr) {
      q[rr][0]=qacc[rr][0]+qb4.x; q[rr][1]=qacc[rr][1]+qb4.y;
      q[rr][2]=qacc[rr][2]+qb4.z; q[rr][3]=qacc[rr][3]+qb4.w;
    }
  }

  // ---------------- attention over history (query = current z) ----------------
  if (STEP > 0) {
    if (A.useKV) {
      #pragma unroll 1
      for (int j = 0; j <= STEP; ++j) {   // scores from cached k_j
        const float* KH = A.H1 + (size_t)j*BD;
        #pragma unroll
        for (int rr = 0; rr < 4; ++rr) {
          float4 kv = ld4(KH + (size_t)(row0 + rg*4 + rr)*D + cg*4);
          float s = q[rr][0]*kv.x + q[rr][1]*kv.y + q[rr][2]*kv.z + q[rr][3]*kv.w;
          s += __shfl_xor(s,1); s += __shfl_xor(s,2); s += __shfl_xor(s,4);
          s += __shfl_xor(s,8); s += __shfl_xor(s,16);
          if (cg == 0) sS[rg*4+rr][j] = s;
        }
      }
    } else {
      #pragma unroll 1
      for (int j = 0; j <= STEP; ++j) {   // scores vs recomputed k_j
        __syncthreads();
        stage_raw(sA, A.H1 + (size_t)j*BD, row0, t);
        __syncthreads();
        float kacc[4][4] = {};
        mm_block<128,4>(A.kw, 128, sA, LDU, rg, cg, kacc);
        float4 kb4 = ld4(A.kb + cg*4);
        #pragma unroll
        for (int rr = 0; rr < 4; ++rr) {
          float s = q[rr][0]*(kacc[rr][0]+kb4.x) + q[rr][1]*(kacc[rr][1]+kb4.y)
                  + q[rr][2]*(kacc[rr][2]+kb4.z) + q[rr][3]*(kacc[rr][3]+kb4.w);
          s += __shfl_xor(s,1); s += __shfl_xor(s,2); s += __shfl_xor(s,4);
          s += __shfl_xor(s,8); s += __shfl_xor(s,16);
          if (cg == 0) sS[rg*4+rr][j] = s;
        }
      }
    }
    __syncthreads();
    if (t < ROWS) { // softmax over <=5 scores
      float mx = -3.0e38f;
      for (int j = 0; j <= STEP; ++j) { float v = sS[t][j]*ATT_SCALE; sS[t][j] = v; mx = fmaxf(mx, v); }
      float sum = 0.f;
      for (int j = 0; j <= STEP; ++j) { float p = expf(sS[t][j]-mx); sS[t][j] = p; sum += p; }
      float inv = 1.f/sum;
      for (int j = 0; j <= STEP; ++j) sS[t][j] *= inv;
    }
    __syncthreads();
    float ao[4][4] = {};
    if (A.useKV) {
      #pragma unroll 1
      for (int j = 0; j <= STEP; ++j) {   // weighted sum of cached v_j
        const float* VH = A.H2 + (size_t)j*BD;
        #pragma unroll
        for (int rr = 0; rr < 4; ++rr) {
          float p = sS[rg*4+rr][j];
          float4 vv = ld4(VH + (size_t)(row0 + rg*4 + rr)*D + cg*4);
          ao[rr][0] += p*vv.x; ao[rr][1] += p*vv.y;
          ao[rr][2] += p*vv.z; ao[rr][3] += p*vv.w;
        }
      }
    } else {
      #pragma unroll 1
      for (int j = 0; j <= STEP; ++j) {   // weighted sum of recomputed v_j
        __syncthreads();
        stage_raw(sA, A.H1 + (size_t)j*BD, row0, t);
        __syncthreads();
        float vacc[4][4] = {};
        mm_block<128,4>(A.vw, 128, sA, LDU, rg, cg, vacc);
        float4 vb4 = ld4(A.vb + cg*4);
        #pragma unroll
        for (int rr = 0; rr < 4; ++rr) {
          float p = sS[rg*4+rr][j];
          ao[rr][0] += p*(vacc[rr][0]+vb4.x);
          ao[rr][1] += p*(vacc[rr][1]+vb4.y);
          ao[rr][2] += p*(vacc[rr][2]+vb4.z);
          ao[rr][3] += p*(vacc[rr][3]+vb4.w);
        }
      }
      __syncthreads();
    }
    #pragma unroll
    for (int rr = 0; rr < 4; ++rr) {
      float4 v; v.x=ao[rr][0]; v.y=ao[rr][1]; v.z=ao[rr][2]; v.w=ao[rr][3];
      st4(sA + (rg*4+rr)*LDU + cg*4, v);
    }
    __syncthreads();
    float oacc[4][4] = {};
    mm_block<128,4>(A.ow, 128, sA, LDU, rg, cg, oacc);
    float4 ob4 = ld4(A.ob + cg*4);
    float add[4][4];
    #pragma unroll
    for (int rr = 0; rr < 4; ++rr) {
      add[rr][0] = oacc[rr][0]+ob4.x;
      add[rr][1] = oacc[rr][1]+ob4.y;
      add[rr][2] = oacc[rr][2]+ob4.z;
      add[rr][3] = oacc[rr][3]+ob4.w;
    }
    z_ln_update(A, row0, rg, cg, add);
    __syncthreads();
  }

  // ---------------- rinse + batch-global partial sums ----------------
  {
    float sxz = 0.f, syr = 0.f;
    for (int e4 = t; e4 < ROWS*32; e4 += NTHR) {
      int r = e4 >> 5, c4 = e4 & 31;
      size_t off = (size_t)(row0+r)*D + c4*4;
      float4 xv = ld4(A.x + off);
      float4 zv = ld4(A.Z + off);   // z pre-faith (fs applied in redK/epilogue)
      float4 yv = ld4(A.Y + off);
      float4 rn;
      rn.x = tanhf(zv.x + yv.x);
      rn.y = tanhf(zv.y + yv.y);
      rn.z = tanhf(zv.z + yv.z);
      rn.w = tanhf(zv.w + yv.w);
      sxz += dot4(xv, zv);
      syr += dot4(yv, rn);
      if (blockIdx.x == 0 && r == 0)
        st4(A.SCAL + SC_R10 + c4*4, rn);   // rinse1[row 0] for memory buffer
    }
    #pragma unroll
    for (int m2 = 1; m2 < 64; m2 <<= 1) { sxz += __shfl_xor(sxz,m2); syr += __shfl_xor(syr,m2); }
    if ((t & 63) == 0) { sRed[t>>6][0] = sxz; sRed[t>>6][1] = syr; }
    __syncthreads();
    if (t == 0) {
      float X = 0.f, Yv = 0.f, G = 0.f;
      #pragma unroll
      for (int w2 = 0; w2 < 4; ++w2) { X += sRed[w2][0]; Yv += sRed[w2][1]; }
      #pragma unroll
      for (int r = 0; r < ROWS; ++r) G += sG[r];
      float* p = A.PART + (size_t)blockIdx.x*4;
      p[0] = G; p[1] = X; p[2] = Yv;
    }
  }
}

template<int STEP>
__global__ void redK(Args A)
{
  __shared__ float sRed[4][3];
  const int t = threadIdx.x;  // 256
  float sg = 0.f, sxz = 0.f, syr = 0.f;
  for (int b = t; b < NBLK; b += 256) {
    const float* p = A.PART + (size_t)b*4;
    sg += p[0]; sxz += p[1]; syr += p[2];
  }
  #pragma unroll
  for (int m = 1; m < 64; m <<= 1) {
    sg  += __shfl_xor(sg,m);
    sxz += __shfl_xor(sxz,m);
    syr += __shfl_xor(syr,m);
  }
  if ((t & 63) == 0) { int w = t>>6; sRed[w][0]=sg; sRed[w][1]=sxz; sRed[w][2]=syr; }
  __syncthreads();
  if (t == 0) {
    float G=0.f, X=0.f, Yv=0.f;
    #pragma unroll
    for (int w = 0; w < 4; ++w) { G += sRed[w][0]; X += sRed[w][1]; Yv += sRed[w][2]; }
    float conf = G * (1.f/(float)BATCH);
    float csum = conf + (STEP == 0 ? 0.f : A.SCAL[SC_CSUM]);
    A.SCAL[SC_CSUM] = csum;
    A.conf[STEP] = conf;
    float faith = sqrtf(csum / (float)(STEP+1));
    float fs = 1.f + 0.05f*faith;
    // bond uses mean(x*z_postfaith) = fs * Sxz/(B*D)
    float bond = tanhf((fs*X + Yv) * (1.f/((float)BATCH*(float)D)));
    A.SCAL[SC_FS]  = fs;
    A.SCAL[SC_B02] = 0.2f*bond;
  }
  if (t < D) {
    float fut = 0.f;
    if (STEP > 0) {
      int lo = (STEP-3 < 0) ? 0 : STEP-3;
      float s = 0.f;
      for (int j = lo; j < STEP; ++j) s += A.SCAL[SC_MEM + j*D + t];
      fut = s / (float)(STEP - lo);
    }
    A.SCAL[SC_FUT + t] = fut;
    // memory[STEP] = tanh(rinse1[0] + 0.3*future)
    A.SCAL[SC_MEM + STEP*D + t] = tanhf(A.SCAL[SC_R10 + t] + 0.3f*fut);
  }
}

__global__ __launch_bounds__(NTHR, 4) void finalK(Args A)
{
  __shared__ __align__(16) float sA[ROWS*LDU];
  __shared__ __align__(16) float sB[ROWS*LDU];
  __shared__ float sM[ROWS], sR[ROWS];
  const int t = threadIdx.x;
  const int row0 = blockIdx.x * ROWS;
  const int rg = t >> 5, cg = t & 31;
  const int r8 = t >> 3, sub = t & 7;

  epilogue_phase(A, sA, sB, sM, sR, row0, t, rg, cg, r8, sub);  // step-4 epilogue

  // pad head: tanh(gelu(z@pw1+pb1)@pw2+pb2)
  stage_raw(sA, A.Z, row0, t);
  __syncthreads();
  float acc[4][2] = {};
  mm_block<128,2>(A.pw1, 64, sA, LDU, rg, cg, acc);
  float2 pb = *(const float2*)(A.pb1 + cg*2);
  #pragma unroll
  for (int rr = 0; rr < 4; ++rr) {
    sB[(rg*4+rr)*LDU + cg*2 + 0] = geluf(acc[rr][0] + pb.x);
    sB[(rg*4+rr)*LDU + cg*2 + 1] = geluf(acc[rr][1] + pb.y);
  }
  __syncthreads();
  {
    float o0=0.f, o1=0.f, o2=0.f;
    #pragma unroll
    for (int jj = 0; jj < 8; ++jj) {
      int j = sub*8 + jj;
      float p = sB[r8*LDU + j];
      o0 += p*A.pw2[j*3+0];
      o1 += p*A.pw2[j*3+1];
      o2 += p*A.pw2[j*3+2];
    }
    o0 += __shfl_xor(o0,1); o0 += __shfl_xor(o0,2); o0 += __shfl_xor(o0,4);
    o1 += __shfl_xor(o1,1); o1 += __shfl_xor(o1,2); o1 += __shfl_xor(o1,4);
    o2 += __shfl_xor(o2,1); o2 += __shfl_xor(o2,2); o2 += __shfl_xor(o2,4);
    if (sub == 0) {
      size_t ro = (size_t)(row0 + r8)*3;
      A.pad[ro+0] = tanhf(o0 + A.pb2[0]);
      A.pad[ro+1] = tanhf(o1 + A.pb2[1]);
      A.pad[ro+2] = tanhf(o2 + A.pb2[2]);
    }
  }
}

extern "C" void kernel_launch(void* const* d_in, const int* in_sizes, int n_in,
                              void* d_out, int out_size, void* d_ws, size_t ws_size,
                              hipStream_t stream)
{
  (void)in_sizes; (void)n_in; (void)out_size;
  Args a;
  a.x      = (const float*)d_in[0];
  a.y_init = (const float*)d_in[1];
  a.affect = (const float*)d_in[2];
  a.g_lat  = (const float*)d_in[3];
  a.b_lat  = (const float*)d_in[4];
  a.g_ans  = (const float*)d_in[5];
  a.b_ans  = (const float*)d_in[6];
  a.g_z    = (const float*)d_in[7];
  a.b_z    = (const float*)d_in[8];
  a.lw1    = (const float*)d_in[9];
  a.lb1    = (const float*)d_in[10];
  a.lw2    = (const float*)d_in[11];
  a.lb2    = (const float*)d_in[12];
  a.aw1    = (const float*)d_in[13];
  a.ab1    = (const float*)d_in[14];
  a.aw2    = (const float*)d_in[15];
  a.ab2    = (const float*)d_in[16];
  a.affw   = (const float*)d_in[17];
  a.affb   = (const float*)d_in[18];
  a.gw     = (const float*)d_in[19];
  a.gb     = (const float*)d_in[20];
  a.qw     = (const float*)d_in[21];
  a.qb     = (const float*)d_in[22];
  a.kw     = (const float*)d_in[23];
  a.kb     = (const float*)d_in[24];
  a.vw     = (const float*)d_in[25];
  a.vb     = (const float*)d_in[26];
  a.ow     = (const float*)d_in[27];
  a.ob     = (const float*)d_in[28];
  a.pw1    = (const float*)d_in[29];
  a.pb1    = (const float*)d_in[30];
  a.pw2    = (const float*)d_in[31];
  a.pb2    = (const float*)d_in[32];
  float* out = (float*)d_out;
  a.Y    = out;
  a.conf = out + BD;
  a.pad  = a.conf + NSTEP;
  float* ws = (float*)d_ws;
  a.Z    = ws + WS_Z;
  a.H1   = ws + WS_H1;
  a.PART = ws + WS_PART;
  a.SCAL = ws + WS_SCAL;
  a.H2   = ws + WS_H2;
  a.useKV = (ws_size >= WS_KV_END * sizeof(float)) ? 1 : 0;

  prepK<<<dim3(2048), dim3(256), 0, stream>>>(a);
  stepK<0><<<dim3(NBLK), dim3(NTHR), 0, stream>>>(a);
  redK<0><<<dim3(1), dim3(256), 0, stream>>>(a);
  stepK<1><<<dim3(NBLK), dim3(NTHR), 0, stream>>>(a);
  redK<1><<<dim3(1), dim3(256), 0, stream>>>(a);
  stepK<2><<<dim3(NBLK), dim3(NTHR), 0, stream>>>(a);
  redK<2><<<dim3(1), dim3(256), 0, stream>>>(a);
  stepK<3><<<dim3(NBLK), dim3(NTHR), 0, stream>>>(a);
  redK<3><<<dim3(1), dim3(256), 0, stream>>>(a);
  stepK<4><<<dim3(NBLK), dim3(NTHR), 0, stream>>>(a);
  redK<4><<<dim3(1), dim3(256), 0, stream>>>(a);
  finalK<<<dim3(NBLK), dim3(NTHR), 0, stream>>>(a);
}

// Round 7
// 7309.013 us; speedup vs baseline: 1.1563x; 1.1563x over previous
//
#include <hip/hip_runtime.h>
#include <math.h>

// TinyRecursiveModelTRMv6 — fp32, round 7.
// Base = round-5 (8.32ms). Single change: big GEMMs whose outputs feed only
// ELEMENTWISE ops (lw1 x3, aw1, aw2) repartitioned from (cg=t&31 x NPT8/4,
// rg=t>>5 x 4 rows) to (cg=t&63 x NPT4/2, rg=t>>6 x 8 rows):
//   - 64 lanes of a wave now cover ALL output cols -> zero intra-wave W-load
//     duplication (was 2x), 4x total block redundancy (was 8x) -> ~37% less
//     L1 weight traffic (the r6-diagnosed bottleneck).
//   - A-operand reads become wave-uniform -> LDS broadcast, conflict-free.
//   - per-accumulator k-order unchanged -> bit-identical results.
// lw2/qkvo/attention/pad/LN/staging/barriers/LDS layout: VERBATIM round-5.
// Launches: prep, (stepK<i>, redK<i>) x5, final.
// ws: recompute fallback >= ~192.1 MiB; KV mode >= ~369.2 MiB (runtime check).

#define BATCH 65536
#define D 128
#define BD ((size_t)BATCH * D)
#define NSTEP 5
#define ROWS 32
#define NTHR 256
#define NBLK (BATCH / ROWS)          // 2048
#define LN_EPS 1e-5f
#define ATT_SCALE 0.08838834764831845f   // 128^-0.5
#define LDA 132
#define LDB 260

// ---- workspace layout (float offsets) ----
#define WS_Z    ((size_t)0)
#define WS_H1   (BD)                              // 5 x B x D : ZH (recompute) or KH (kv)
#define WS_PART (WS_H1 + 5*BD)                    // NBLK x 4
#define WS_SCAL (WS_PART + (size_t)NBLK*4)        // 2048 floats
#define WS_H2   (WS_SCAL + 2048)                  // 5 x B x D : VH (kv mode only)
#define WS_KV_END (WS_H2 + 5*BD)

// scalar-block sub-offsets (floats)
#define SC_FS   0
#define SC_B02  1
#define SC_CSUM 2
#define SC_FUT  16
#define SC_MEM  256
#define SC_R10  960

struct Args {
  const float *x, *y_init, *affect;
  const float *g_lat, *b_lat, *g_ans, *b_ans, *g_z, *b_z;
  const float *lw1, *lb1, *lw2, *lb2;
  const float *aw1, *ab1, *aw2, *ab2;
  const float *affw, *affb, *gw, *gb;
  const float *qw, *qb, *kw, *kb, *vw, *vb, *ow, *ob;
  const float *pw1, *pb1, *pw2, *pb2;
  float *Y, *conf, *pad;            // d_out regions
  float *Z, *H1, *H2, *PART, *SCAL; // ws regions
  int useKV;
};

__device__ __forceinline__ float4 ld4(const float* p) { return *(const float4*)p; }
__device__ __forceinline__ void st4(float* p, float4 v) { *(float4*)p = v; }
__device__ __forceinline__ float geluf(float v) { return 0.5f*v*(1.0f + erff(v*0.70710678118654752f)); }
__device__ __forceinline__ float dot4(float4 a, float4 b){ return a.x*b.x + a.y*b.y + a.z*b.z + a.w*b.w; }
__device__ __forceinline__ void accSQ(float4 v, float& S, float& Q) {
  S += v.x+v.y+v.z+v.w;
  Q += v.x*v.x + v.y*v.y + v.z*v.z + v.w*v.w;
}
__device__ __forceinline__ float getf(const float4& v, int i) {
  return i==0 ? v.x : (i==1 ? v.y : (i==2 ? v.z : v.w));
}

// Register-tiled block GEMM: RPT rows x NPT cols per thread. A staged in LDS
// [32][lda] (rows rbase..rbase+RPT), W streamed row-major [KDIM][N] from global.
// Per-accumulator FMA order is k-ascending (bit-identical across partitions).
template<int KDIM, int NPT, int RPT>
__device__ __forceinline__ void mm_block(const float* __restrict__ W, int N,
                                         const float* As, int lda,
                                         int rbase, int cg, float (&acc)[RPT][NPT])
{
  const float* wp = W + cg*NPT;
  #pragma unroll 2
  for (int k4 = 0; k4 < KDIM/4; ++k4) {
    float4 av[RPT];
    #pragma unroll
    for (int rr = 0; rr < RPT; ++rr)
      av[rr] = ld4(As + (rbase+rr)*lda + k4*4);
    #pragma unroll
    for (int kk = 0; kk < 4; ++kk) {
      const int k = k4*4 + kk;
      float w[NPT];
      if constexpr (NPT == 8) {
        float4 w0 = ld4(wp + (size_t)k*N);
        float4 w1 = ld4(wp + (size_t)k*N + 4);
        w[0]=w0.x; w[1]=w0.y; w[2]=w0.z; w[3]=w0.w;
        w[4]=w1.x; w[5]=w1.y; w[6]=w1.z; w[7]=w1.w;
      } else if constexpr (NPT == 4) {
        float4 w0 = ld4(wp + (size_t)k*N);
        w[0]=w0.x; w[1]=w0.y; w[2]=w0.z; w[3]=w0.w;
      } else {
        float2 w0 = *(const float2*)(wp + (size_t)k*N);
        w[0]=w0.x; w[1]=w0.y;
      }
      #pragma unroll
      for (int rr = 0; rr < RPT; ++rr) {
        float e = getf(av[rr], kk);
        #pragma unroll
        for (int c = 0; c < NPT; ++c)
          acc[rr][c] += e*w[c];
      }
    }
  }
}

// z = LN(z + add) over d=128 (reads/writes global Z). OLD map (rgO,cgO).
__device__ __forceinline__ void z_ln_update(const Args& A, int row0, int rgO, int cgO,
                                            const float (&add)[4][4])
{
  float4 g4 = ld4(A.g_z + cgO*4);
  float4 b4 = ld4(A.b_z + cgO*4);
  #pragma unroll
  for (int rr = 0; rr < 4; ++rr) {
    size_t off = (size_t)(row0 + rgO*4 + rr)*D + cgO*4;
    float4 z = ld4(A.Z + off);
    float v0 = z.x + add[rr][0];
    float v1 = z.y + add[rr][1];
    float v2 = z.z + add[rr][2];
    float v3 = z.w + add[rr][3];
    float S = v0+v1+v2+v3;
    float Q = v0*v0+v1*v1+v2*v2+v3*v3;
    S += __shfl_xor(S,1);  Q += __shfl_xor(Q,1);
    S += __shfl_xor(S,2);  Q += __shfl_xor(Q,2);
    S += __shfl_xor(S,4);  Q += __shfl_xor(Q,4);
    S += __shfl_xor(S,8);  Q += __shfl_xor(Q,8);
    S += __shfl_xor(S,16); Q += __shfl_xor(Q,16);
    float m  = S*(1.f/128.f);
    float rs = rsqrtf(Q*(1.f/128.f) - m*m + LN_EPS);
    float4 o;
    o.x = (v0-m)*rs*g4.x + b4.x;
    o.y = (v1-m)*rs*g4.y + b4.y;
    o.z = (v2-m)*rs*g4.z + b4.z;
    o.w = (v3-m)*rs*g4.w + b4.w;
    st4(A.Z + off, o);
  }
}

__device__ __forceinline__ void stage_raw(float* sA, const float* src, int row0, int t)
{
  for (int e4 = t; e4 < ROWS*32; e4 += NTHR) {
    int r = e4 >> 5, c4 = e4 & 31;
    st4(sA + r*LDA + c4*4, ld4(src + (size_t)(row0+r)*D + c4*4));
  }
}

// Epilogue of previous outer step: z = (z*fs)*(1-b02)+b02*future ; answer LN+MLP ; y += 0.4*dy
// aw1/aw2 use the NEW wide-col partition (rgN=t>>6 x 8 rows, cgN=t&63).
__device__ __forceinline__ void epilogue_phase(const Args& A, float* sB, float* sM, float* sR,
                                               int row0, int t, int rgN, int cgN,
                                               int r8, int sub)
{
  const float fs  = A.SCAL[SC_FS];
  const float b02 = A.SCAL[SC_B02];
  const float a   = fs*(1.0f - b02);
  for (int e4 = t; e4 < ROWS*32; e4 += NTHR) {
    int r = e4 >> 5, c4 = e4 & 31;
    size_t off = (size_t)(row0 + r)*D + c4*4;
    float4 z = ld4(A.Z + off);
    float4 f = ld4(A.SCAL + SC_FUT + c4*4);
    z.x = z.x*a + b02*f.x;
    z.y = z.y*a + b02*f.y;
    z.z = z.z*a + b02*f.z;
    z.w = z.w*a + b02*f.w;
    st4(A.Z + off, z);
  }
  __syncthreads();
  { // LN stats over [y,z] (256)
    const float* yr = A.Y + (size_t)(row0 + r8)*D;
    const float* zr = A.Z + (size_t)(row0 + r8)*D;
    float S = 0.f, Q = 0.f;
    #pragma unroll
    for (int j = 0; j < 4; ++j) {
      int c = (sub + 8*j)*4;
      accSQ(ld4(yr + c), S, Q);
      accSQ(ld4(zr + c), S, Q);
    }
    S += __shfl_xor(S,1); Q += __shfl_xor(Q,1);
    S += __shfl_xor(S,2); Q += __shfl_xor(Q,2);
    S += __shfl_xor(S,4); Q += __shfl_xor(Q,4);
    if (sub == 0) {
      float m = S*(1.f/256.f);
      sM[r8] = m;
      sR[r8] = rsqrtf(Q*(1.f/256.f) - m*m + LN_EPS);
    }
  }
  __syncthreads();
  // stage ai = LN([y,z])*g+b into sB (256 wide)
  for (int e4 = t; e4 < ROWS*64; e4 += NTHR) {
    int r = e4 >> 6, c4 = e4 & 63;
    int k = c4*4;
    float m = sM[r], rs = sR[r];
    float4 v = (k < D) ? ld4(A.Y + (size_t)(row0+r)*D + k)
                       : ld4(A.Z + (size_t)(row0+r)*D + (k - D));
    float4 g = ld4(A.g_ans + k);
    float4 b = ld4(A.b_ans + k);
    float4 o;
    o.x = (v.x-m)*rs*g.x + b.x;
    o.y = (v.y-m)*rs*g.y + b.y;
    o.z = (v.z-m)*rs*g.z + b.z;
    o.w = (v.w-m)*rs*g.w + b.w;
    st4(sB + r*LDB + k, o);
  }
  __syncthreads();
  float acc[8][4] = {};
  mm_block<256,4,8>(A.aw1, 256, sB, LDB, rgN*8, cgN, acc);
  float4 b1 = ld4(A.ab1 + cgN*4);
  float h[8][4];
  #pragma unroll
  for (int rr = 0; rr < 8; ++rr) {
    h[rr][0]=geluf(acc[rr][0]+b1.x); h[rr][1]=geluf(acc[rr][1]+b1.y);
    h[rr][2]=geluf(acc[rr][2]+b1.z); h[rr][3]=geluf(acc[rr][3]+b1.w);
  }
  __syncthreads();
  #pragma unroll
  for (int rr = 0; rr < 8; ++rr) {
    float4 hv; hv.x=h[rr][0]; hv.y=h[rr][1]; hv.z=h[rr][2]; hv.w=h[rr][3];
    st4(sB + (rgN*8+rr)*LDB + cgN*4, hv);
  }
  __syncthreads();
  float acc2[8][2] = {};
  mm_block<256,2,8>(A.aw2, 128, sB, LDB, rgN*8, cgN, acc2);
  float2 b2 = *(const float2*)(A.ab2 + cgN*2);
  #pragma unroll
  for (int rr = 0; rr < 8; ++rr) {
    size_t off = (size_t)(row0 + rgN*8 + rr)*D + cgN*2;
    float2 y = *(const float2*)(A.Y + off);
    y.x += 0.4f*(acc2[rr][0] + b2.x);
    y.y += 0.4f*(acc2[rr][1] + b2.y);
    *(float2*)(A.Y + off) = y;
  }
  __syncthreads();
}

__global__ void prepK(Args A)
{
  size_t i  = (size_t)blockIdx.x*blockDim.x + threadIdx.x;
  size_t n4 = BD/4;
  float4 zero; zero.x=0.f; zero.y=0.f; zero.z=0.f; zero.w=0.f;
  for (; i < n4; i += (size_t)gridDim.x*blockDim.x) {
    ((float4*)A.Z)[i] = zero;
    ((float4*)A.Y)[i] = ((const float4*)A.y_init)[i];
  }
}

template<int STEP>
__global__ __launch_bounds__(NTHR, 3) void stepK(Args A)
{
  __shared__ __align__(16) float sA[ROWS*LDA];
  __shared__ __align__(16) float sB[ROWS*LDB];
  __shared__ float sM[ROWS], sR[ROWS], sG[ROWS];
  __shared__ float sS[ROWS][8];
  __shared__ float sRed[4][2];

  const int t = threadIdx.x;
  const int row0 = blockIdx.x * ROWS;
  const int rgO = t >> 5, cgO = t & 31;   // old partition (4 rows x 4/8 cols)
  const int rgN = t >> 6, cgN = t & 63;   // new partition (8 rows x 4/2 cols)
  const int r8 = t >> 3, sub = t & 7;

  if (STEP > 0)
    epilogue_phase(A, sB, sM, sR, row0, t, rgN, cgN, r8, sub);

  // ---------------- inner latent loop (x4) ----------------
  #pragma unroll 1
  for (int it = 0; it < 4; ++it) {
    { // stats over cat384 = [x,y,z]
      const float* xr = A.x + (size_t)(row0 + r8)*D;
      const float* yr = A.Y + (size_t)(row0 + r8)*D;
      const float* zr = A.Z + (size_t)(row0 + r8)*D;
      float S = 0.f, Q = 0.f;
      #pragma unroll
      for (int j = 0; j < 4; ++j) {
        int c = (sub + 8*j)*4;
        accSQ(ld4(xr + c), S, Q);
        accSQ(ld4(yr + c), S, Q);
        accSQ(ld4(zr + c), S, Q);
      }
      S += __shfl_xor(S,1); Q += __shfl_xor(Q,1);
      S += __shfl_xor(S,2); Q += __shfl_xor(Q,2);
      S += __shfl_xor(S,4); Q += __shfl_xor(Q,4);
      if (sub == 0) {
        float m = S*(1.f/384.f);
        sM[r8] = m;
        sR[r8] = rsqrtf(Q*(1.f/384.f) - m*m + LN_EPS);
      }
    }
    __syncthreads();
    float acc[8][4] = {};
    #pragma unroll 1
    for (int seg = 0; seg < 3; ++seg) {  // 384 = x|y|z segments of 128
      const float* src = (seg == 0) ? A.x : (seg == 1 ? (const float*)A.Y : (const float*)A.Z);
      for (int e4 = t; e4 < ROWS*32; e4 += NTHR) {
        int r = e4 >> 5, c4 = e4 & 31;
        float4 v = ld4(src + (size_t)(row0+r)*D + c4*4);
        float m = sM[r], rs = sR[r];
        int k = seg*D + c4*4;
        float4 g = ld4(A.g_lat + k);
        float4 b = ld4(A.b_lat + k);
        float4 o;
        o.x = (v.x-m)*rs*g.x + b.x;
        o.y = (v.y-m)*rs*g.y + b.y;
        o.z = (v.z-m)*rs*g.z + b.z;
        o.w = (v.w-m)*rs*g.w + b.w;
        st4(sA + r*LDA + c4*4, o);
      }
      __syncthreads();
      mm_block<128,4,8>(A.lw1 + (size_t)seg*D*256, 256, sA, LDA, rgN*8, cgN, acc);
      __syncthreads();
    }
    float4 l1 = ld4(A.lb1 + cgN*4);
    #pragma unroll
    for (int rr = 0; rr < 8; ++rr) {
      float4 h;
      h.x = geluf(acc[rr][0]+l1.x);
      h.y = geluf(acc[rr][1]+l1.y);
      h.z = geluf(acc[rr][2]+l1.z);
      h.w = geluf(acc[rr][3]+l1.w);
      st4(sB + (rgN*8+rr)*LDB + cgN*4, h);
    }
    __syncthreads();
    float acc2[4][4] = {};
    mm_block<256,4,4>(A.lw2, 128, sB, LDB, rgO*4, cgO, acc2);
    float4 l2 = ld4(A.lb2 + cgO*4);
    float add[4][4];
    #pragma unroll
    for (int rr = 0; rr < 4; ++rr) {
      add[rr][0] = 0.3f*(acc2[rr][0]+l2.x);
      add[rr][1] = 0.3f*(acc2[rr][1]+l2.y);
      add[rr][2] = 0.3f*(acc2[rr][2]+l2.z);
      add[rr][3] = 0.3f*(acc2[rr][3]+l2.w);
    }
    z_ln_update(A, row0, rgO, cgO, add);
    __syncthreads();
  }

  // ---------------- gate + affect ----------------
  {
    size_t row = (size_t)row0 + r8;
    const float* zr = A.Z + row*D;
    float af0 = A.affect[row*3+0];
    float af1 = A.affect[row*3+1];
    float af2 = A.affect[row*3+2];
    float dg = 0.f;
    #pragma unroll
    for (int j = 0; j < 4; ++j) {
      int c = (sub + 8*j)*4;
      float4 zv = ld4(zr + c);
      float4 g1 = ld4(A.gw + c);
      float4 g2 = ld4(A.gw + D + c);
      float4 w0 = ld4(A.affw + c);
      float4 w1 = ld4(A.affw + D + c);
      float4 w2 = ld4(A.affw + 2*D + c);
      float4 ab = ld4(A.affb + c);
      float4 al;
      al.x = tanhf(af0*w0.x + af1*w1.x + af2*w2.x + ab.x);
      al.y = tanhf(af0*w0.y + af1*w1.y + af2*w2.y + ab.y);
      al.z = tanhf(af0*w0.z + af1*w1.z + af2*w2.z + ab.z);
      al.w = tanhf(af0*w0.w + af1*w1.w + af2*w2.w + ab.w);
      st4(sA + r8*LDA + c, al);   // cache affect_latent for z-update
      dg += dot4(zv, g1) + dot4(al, g2);
    }
    dg += __shfl_xor(dg,1);
    dg += __shfl_xor(dg,2);
    dg += __shfl_xor(dg,4);
    if (sub == 0) sG[r8] = 1.f/(1.f + expf(-(dg + A.gb[0])));
  }
  __syncthreads();
  { // z += 0.3*gate*al ; recompute mode records z snapshot
    float* zhw = A.H1 + (size_t)STEP*BD;
    for (int e4 = t; e4 < ROWS*32; e4 += NTHR) {
      int r = e4 >> 5, c4 = e4 & 31;
      size_t off = (size_t)(row0+r)*D + c4*4;
      float4 z  = ld4(A.Z + off);
      float4 al = ld4(sA + r*LDA + c4*4);
      float g = 0.3f * sG[r];
      z.x += g*al.x; z.y += g*al.y; z.z += g*al.z; z.w += g*al.w;
      st4(A.Z + off, z);
      if (!A.useKV) st4(zhw + off, z);
    }
  }
  __syncthreads();

  // ---------------- snapshot staging: K/V cache + q (old partition) ----------------
  float q[4][4];
  if (A.useKV || STEP > 0) {
    stage_raw(sA, A.Z, row0, t);
    __syncthreads();
  }
  if (A.useKV) {
    float kacc[4][4] = {}, vacc[4][4] = {};
    mm_block<128,4,4>(A.kw, 128, sA, LDA, rgO*4, cgO, kacc);
    mm_block<128,4,4>(A.vw, 128, sA, LDA, rgO*4, cgO, vacc);
    float4 kb4 = ld4(A.kb + cgO*4);
    float4 vb4 = ld4(A.vb + cgO*4);
    float* KH = A.H1 + (size_t)STEP*BD;
    float* VH = A.H2 + (size_t)STEP*BD;
    #pragma unroll
    for (int rr = 0; rr < 4; ++rr) {
      size_t off = (size_t)(row0 + rgO*4 + rr)*D + cgO*4;
      float4 kv; kv.x=kacc[rr][0]+kb4.x; kv.y=kacc[rr][1]+kb4.y;
                 kv.z=kacc[rr][2]+kb4.z; kv.w=kacc[rr][3]+kb4.w;
      float4 vv; vv.x=vacc[rr][0]+vb4.x; vv.y=vacc[rr][1]+vb4.y;
                 vv.z=vacc[rr][2]+vb4.z; vv.w=vacc[rr][3]+vb4.w;
      st4(KH + off, kv);   // read back only by this same thread (j==STEP)
      st4(VH + off, vv);
    }
  }
  if (STEP > 0) {
    float qacc[4][4] = {};
    mm_block<128,4,4>(A.qw, 128, sA, LDA, rgO*4, cgO, qacc);
    float4 qb4 = ld4(A.qb + cgO*4);
    #pragma unroll
    for (int rr = 0; rr < 4; ++rr) {
      q[rr][0]=qacc[rr][0]+qb4.x; q[rr][1]=qacc[rr][1]+qb4.y;
      q[rr][2]=qacc[rr][2]+qb4.z; q[rr][3]=qacc[rr][3]+qb4.w;
    }
  }

  // ---------------- attention over history (query = current z) ----------------
  if (STEP > 0) {
    if (A.useKV) {
      #pragma unroll 1
      for (int j = 0; j <= STEP; ++j) {   // scores from cached k_j
        const float* KH = A.H1 + (size_t)j*BD;
        #pragma unroll
        for (int rr = 0; rr < 4; ++rr) {
          float4 kv = ld4(KH + (size_t)(row0 + rgO*4 + rr)*D + cgO*4);
          float s = q[rr][0]*kv.x + q[rr][1]*kv.y + q[rr][2]*kv.z + q[rr][3]*kv.w;
          s += __shfl_xor(s,1); s += __shfl_xor(s,2); s += __shfl_xor(s,4);
          s += __shfl_xor(s,8); s += __shfl_xor(s,16);
          if (cgO == 0) sS[rgO*4+rr][j] = s;
        }
      }
    } else {
      #pragma unroll 1
      for (int j = 0; j <= STEP; ++j) {   // scores vs recomputed k_j
        __syncthreads();
        stage_raw(sA, A.H1 + (size_t)j*BD, row0, t);
        __syncthreads();
        float kacc[4][4] = {};
        mm_block<128,4,4>(A.kw, 128, sA, LDA, rgO*4, cgO, kacc);
        float4 kb4 = ld4(A.kb + cgO*4);
        #pragma unroll
        for (int rr = 0; rr < 4; ++rr) {
          float s = q[rr][0]*(kacc[rr][0]+kb4.x) + q[rr][1]*(kacc[rr][1]+kb4.y)
                  + q[rr][2]*(kacc[rr][2]+kb4.z) + q[rr][3]*(kacc[rr][3]+kb4.w);
          s += __shfl_xor(s,1); s += __shfl_xor(s,2); s += __shfl_xor(s,4);
          s += __shfl_xor(s,8); s += __shfl_xor(s,16);
          if (cgO == 0) sS[rgO*4+rr][j] = s;
        }
      }
    }
    __syncthreads();
    if (t < ROWS) { // softmax over <=5 scores
      float mx = -3.0e38f;
      for (int j = 0; j <= STEP; ++j) { float v = sS[t][j]*ATT_SCALE; sS[t][j] = v; mx = fmaxf(mx, v); }
      float sum = 0.f;
      for (int j = 0; j <= STEP; ++j) { float p = expf(sS[t][j]-mx); sS[t][j] = p; sum += p; }
      float inv = 1.f/sum;
      for (int j = 0; j <= STEP; ++j) sS[t][j] *= inv;
    }
    __syncthreads();
    float ao[4][4] = {};
    if (A.useKV) {
      #pragma unroll 1
      for (int j = 0; j <= STEP; ++j) {   // weighted sum of cached v_j
        const float* VH = A.H2 + (size_t)j*BD;
        #pragma unroll
        for (int rr = 0; rr < 4; ++rr) {
          float p = sS[rgO*4+rr][j];
          float4 vv = ld4(VH + (size_t)(row0 + rgO*4 + rr)*D + cgO*4);
          ao[rr][0] += p*vv.x; ao[rr][1] += p*vv.y;
          ao[rr][2] += p*vv.z; ao[rr][3] += p*vv.w;
        }
      }
    } else {
      #pragma unroll 1
      for (int j = 0; j <= STEP; ++j) {   // weighted sum of recomputed v_j
        __syncthreads();
        stage_raw(sA, A.H1 + (size_t)j*BD, row0, t);
        __syncthreads();
        float vacc[4][4] = {};
        mm_block<128,4,4>(A.vw, 128, sA, LDA, rgO*4, cgO, vacc);
        float4 vb4 = ld4(A.vb + cgO*4);
        #pragma unroll
        for (int rr = 0; rr < 4; ++rr) {
          float p = sS[rgO*4+rr][j];
          ao[rr][0] += p*(vacc[rr][0]+vb4.x);
          ao[rr][1] += p*(vacc[rr][1]+vb4.y);
          ao[rr][2] += p*(vacc[rr][2]+vb4.z);
          ao[rr][3] += p*(vacc[rr][3]+vb4.w);
        }
      }
      __syncthreads();
    }
    #pragma unroll
    for (int rr = 0; rr < 4; ++rr) {
      float4 v; v.x=ao[rr][0]; v.y=ao[rr][1]; v.z=ao[rr][2]; v.w=ao[rr][3];
      st4(sA + (rgO*4+rr)*LDA + cgO*4, v);
    }
    __syncthreads();
    float oacc[4][4] = {};
    mm_block<128,4,4>(A.ow, 128, sA, LDA, rgO*4, cgO, oacc);
    float4 ob4 = ld4(A.ob + cgO*4);
    float add[4][4];
    #pragma unroll
    for (int rr = 0; rr < 4; ++rr) {
      add[rr][0] = oacc[rr][0]+ob4.x;
      add[rr][1] = oacc[rr][1]+ob4.y;
      add[rr][2] = oacc[rr][2]+ob4.z;
      add[rr][3] = oacc[rr][3]+ob4.w;
    }
    z_ln_update(A, row0, rgO, cgO, add);
    __syncthreads();
  }

  // ---------------- rinse + batch-global partial sums ----------------
  {
    float sxz = 0.f, syr = 0.f;
    for (int e4 = t; e4 < ROWS*32; e4 += NTHR) {
      int r = e4 >> 5, c4 = e4 & 31;
      size_t off = (size_t)(row0+r)*D + c4*4;
      float4 xv = ld4(A.x + off);
      float4 zv = ld4(A.Z + off);   // z pre-faith (fs applied in redK/epilogue)
      float4 yv = ld4(A.Y + off);
      float4 rn;
      rn.x = tanhf(zv.x + yv.x);
      rn.y = tanhf(zv.y + yv.y);
      rn.z = tanhf(zv.z + yv.z);
      rn.w = tanhf(zv.w + yv.w);
      sxz += dot4(xv, zv);
      syr += dot4(yv, rn);
      if (blockIdx.x == 0 && r == 0)
        st4(A.SCAL + SC_R10 + c4*4, rn);   // rinse1[row 0] for memory buffer
    }
    #pragma unroll
    for (int m2 = 1; m2 < 64; m2 <<= 1) { sxz += __shfl_xor(sxz,m2); syr += __shfl_xor(syr,m2); }
    if ((t & 63) == 0) { sRed[t>>6][0] = sxz; sRed[t>>6][1] = syr; }
    __syncthreads();
    if (t == 0) {
      float X = 0.f, Yv = 0.f, G = 0.f;
      #pragma unroll
      for (int w2 = 0; w2 < 4; ++w2) { X += sRed[w2][0]; Yv += sRed[w2][1]; }
      #pragma unroll
      for (int r = 0; r < ROWS; ++r) G += sG[r];
      float* p = A.PART + (size_t)blockIdx.x*4;
      p[0] = G; p[1] = X; p[2] = Yv;
    }
  }
}

template<int STEP>
__global__ void redK(Args A)
{
  __shared__ float sRed[4][3];
  const int t = threadIdx.x;  // 256
  float sg = 0.f, sxz = 0.f, syr = 0.f;
  for (int b = t; b < NBLK; b += 256) {
    const float* p = A.PART + (size_t)b*4;
    sg += p[0]; sxz += p[1]; syr += p[2];
  }
  #pragma unroll
  for (int m = 1; m < 64; m <<= 1) {
    sg  += __shfl_xor(sg,m);
    sxz += __shfl_xor(sxz,m);
    syr += __shfl_xor(syr,m);
  }
  if ((t & 63) == 0) { int w = t>>6; sRed[w][0]=sg; sRed[w][1]=sxz; sRed[w][2]=syr; }
  __syncthreads();
  if (t == 0) {
    float G=0.f, X=0.f, Yv=0.f;
    #pragma unroll
    for (int w = 0; w < 4; ++w) { G += sRed[w][0]; X += sRed[w][1]; Yv += sRed[w][2]; }
    float conf = G * (1.f/(float)BATCH);
    float csum = conf + (STEP == 0 ? 0.f : A.SCAL[SC_CSUM]);
    A.SCAL[SC_CSUM] = csum;
    A.conf[STEP] = conf;
    float faith = sqrtf(csum / (float)(STEP+1));
    float fs = 1.f + 0.05f*faith;
    // bond uses mean(x*z_postfaith) = fs * Sxz/(B*D)
    float bond = tanhf((fs*X + Yv) * (1.f/((float)BATCH*(float)D)));
    A.SCAL[SC_FS]  = fs;
    A.SCAL[SC_B02] = 0.2f*bond;
  }
  if (t < D) {
    float fut = 0.f;
    if (STEP > 0) {
      int lo = (STEP-3 < 0) ? 0 : STEP-3;
      float s = 0.f;
      for (int j = lo; j < STEP; ++j) s += A.SCAL[SC_MEM + j*D + t];
      fut = s / (float)(STEP - lo);
    }
    A.SCAL[SC_FUT + t] = fut;
    // memory[STEP] = tanh(rinse1[0] + 0.3*future)
    A.SCAL[SC_MEM + STEP*D + t] = tanhf(A.SCAL[SC_R10 + t] + 0.3f*fut);
  }
}

__global__ __launch_bounds__(NTHR, 3) void finalK(Args A)
{
  __shared__ __align__(16) float sA[ROWS*LDA];
  __shared__ __align__(16) float sB[ROWS*LDB];
  __shared__ float sM[ROWS], sR[ROWS];
  const int t = threadIdx.x;
  const int row0 = blockIdx.x * ROWS;
  const int rgO = t >> 5, cgO = t & 31;
  const int rgN = t >> 6, cgN = t & 63;
  const int r8 = t >> 3, sub = t & 7;

  epilogue_phase(A, sB, sM, sR, row0, t, rgN, cgN, r8, sub);  // step-4 epilogue

  // pad head: tanh(gelu(z@pw1+pb1)@pw2+pb2)   (old partition, unchanged)
  stage_raw(sA, A.Z, row0, t);
  __syncthreads();
  float acc[4][2] = {};
  mm_block<128,2,4>(A.pw1, 64, sA, LDA, rgO*4, cgO, acc);
  float2 pb = *(const float2*)(A.pb1 + cgO*2);
  #pragma unroll
  for (int rr = 0; rr < 4; ++rr) {
    sB[(rgO*4+rr)*LDB + cgO*2 + 0] = geluf(acc[rr][0] + pb.x);
    sB[(rgO*4+rr)*LDB + cgO*2 + 1] = geluf(acc[rr][1] + pb.y);
  }
  __syncthreads();
  {
    float o0=0.f, o1=0.f, o2=0.f;
    #pragma unroll
    for (int jj = 0; jj < 8; ++jj) {
      int j = sub*8 + jj;
      float p = sB[r8*LDB + j];
      o0 += p*A.pw2[j*3+0];
      o1 += p*A.pw2[j*3+1];
      o2 += p*A.pw2[j*3+2];
    }
    o0 += __shfl_xor(o0,1); o0 += __shfl_xor(o0,2); o0 += __shfl_xor(o0,4);
    o1 += __shfl_xor(o1,1); o1 += __shfl_xor(o1,2); o1 += __shfl_xor(o1,4);
    o2 += __shfl_xor(o2,1); o2 += __shfl_xor(o2,2); o2 += __shfl_xor(o2,4);
    if (sub == 0) {
      size_t ro = (size_t)(row0 + r8)*3;
      A.pad[ro+0] = tanhf(o0 + A.pb2[0]);
      A.pad[ro+1] = tanhf(o1 + A.pb2[1]);
      A.pad[ro+2] = tanhf(o2 + A.pb2[2]);
    }
  }
}

extern "C" void kernel_launch(void* const* d_in, const int* in_sizes, int n_in,
                              void* d_out, int out_size, void* d_ws, size_t ws_size,
                              hipStream_t stream)
{
  (void)in_sizes; (void)n_in; (void)out_size;
  Args a;
  a.x      = (const float*)d_in[0];
  a.y_init = (const float*)d_in[1];
  a.affect = (const float*)d_in[2];
  a.g_lat  = (const float*)d_in[3];
  a.b_lat  = (const float*)d_in[4];
  a.g_ans  = (const float*)d_in[5];
  a.b_ans  = (const float*)d_in[6];
  a.g_z    = (const float*)d_in[7];
  a.b_z    = (const float*)d_in[8];
  a.lw1    = (const float*)d_in[9];
  a.lb1    = (const float*)d_in[10];
  a.lw2    = (const float*)d_in[11];
  a.lb2    = (const float*)d_in[12];
  a.aw1    = (const float*)d_in[13];
  a.ab1    = (const float*)d_in[14];
  a.aw2    = (const float*)d_in[15];
  a.ab2    = (const float*)d_in[16];
  a.affw   = (const float*)d_in[17];
  a.affb   = (const float*)d_in[18];
  a.gw     = (const float*)d_in[19];
  a.gb     = (const float*)d_in[20];
  a.qw     = (const float*)d_in[21];
  a.qb     = (const float*)d_in[22];
  a.kw     = (const float*)d_in[23];
  a.kb     = (const float*)d_in[24];
  a.vw     = (const float*)d_in[25];
  a.vb     = (const float*)d_in[26];
  a.ow     = (const float*)d_in[27];
  a.ob     = (const float*)d_in[28];
  a.pw1    = (const float*)d_in[29];
  a.pb1    = (const float*)d_in[30];
  a.pw2    = (const float*)d_in[31];
  a.pb2    = (const float*)d_in[32];
  float* out = (float*)d_out;
  a.Y    = out;
  a.conf = out + BD;
  a.pad  = a.conf + NSTEP;
  float* ws = (float*)d_ws;
  a.Z    = ws + WS_Z;
  a.H1   = ws + WS_H1;
  a.PART = ws + WS_PART;
  a.SCAL = ws + WS_SCAL;
  a.H2   = ws + WS_H2;
  a.useKV = (ws_size >= WS_KV_END * sizeof(float)) ? 1 : 0;

  prepK<<<dim3(2048), dim3(256), 0, stream>>>(a);
  stepK<0><<<dim3(NBLK), dim3(NTHR), 0, stream>>>(a);
  redK<0><<<dim3(1), dim3(256), 0, stream>>>(a);
  stepK<1><<<dim3(NBLK), dim3(NTHR), 0, stream>>>(a);
  redK<1><<<dim3(1), dim3(256), 0, stream>>>(a);
  stepK<2><<<dim3(NBLK), dim3(NTHR), 0, stream>>>(a);
  redK<2><<<dim3(1), dim3(256), 0, stream>>>(a);
  stepK<3><<<dim3(NBLK), dim3(NTHR), 0, stream>>>(a);
  redK<3><<<dim3(1), dim3(256), 0, stream>>>(a);
  stepK<4><<<dim3(NBLK), dim3(NTHR), 0, stream>>>(a);
  redK<4><<<dim3(1), dim3(256), 0, stream>>>(a);
  finalK<<<dim3(NBLK), dim3(NTHR), 0, stream>>>(a);
}